// Round 8
// baseline (248.945 us; speedup 1.0000x reference)
//
#include <hip/hip_runtime.h>
#include <hip/hip_bf16.h>

#define B_    128
#define N_    196
#define HDIM  512
#define VDIM  2048
#define ATT   512
#define M_TOT (B_ * N_)   // 25088

#define BKK 64             // K step (64 bf16 = 128B = 8 chunks of 16B)
#define NT  (VDIM / BKK)   // 32 K-steps
#define BM1 128
#define BN1 128

typedef float  f32x4  __attribute__((ext_vector_type(4)));
typedef __bf16 bf16x8 __attribute__((ext_vector_type(8)));

__device__ __forceinline__ void gload_lds16(const void* g, void* l) {
    __builtin_amdgcn_global_load_lds(
        (const __attribute__((address_space(1))) void*)g,
        (__attribute__((address_space(3))) void*)l, 16, 0, 0);
}

__device__ __forceinline__ float fast_tanh(float x) {
    float ax = fabsf(x);
    float e  = __expf(-2.f * ax);          // in (0,1], no overflow
    float t  = (1.f - e) / (1.f + e);
    return copysignf(t, x);
}

// ---------------------------------------------------------------------------
// Kernel P: blocks [0,256): Uw transpose -> UwT bf16; [256,384): whp.
// ---------------------------------------------------------------------------
__global__ void k_prep(const float* __restrict__ Uw, __bf16* __restrict__ UwT,
                       const float* __restrict__ h, const float* __restrict__ Ww,
                       const float* __restrict__ Wb, const float* __restrict__ Ub,
                       float* __restrict__ whp) {
    int t = threadIdx.x;  // 256
    if (blockIdx.x < 256) {
        __shared__ __bf16 st[64][65];
        int k0 = (blockIdx.x & 31) * 64;
        int c0 = (blockIdx.x >> 5) * 64;
#pragma unroll
        for (int i = 0; i < 16; ++i) {
            int lin = i * 256 + t;
            int kk = lin >> 6, cc = lin & 63;
            st[kk][cc] = (__bf16)Uw[(size_t)(k0 + kk) * ATT + c0 + cc];
        }
        __syncthreads();
#pragma unroll
        for (int i = 0; i < 16; ++i) {
            int lin = i * 256 + t;
            int cc = lin >> 6, kk = lin & 63;
            UwT[(size_t)(c0 + cc) * VDIM + k0 + kk] = st[kk][cc];
        }
    } else {
        __shared__ float hs[HDIM];
        int b = blockIdx.x - 256;
        hs[t]       = h[(size_t)b * HDIM + t];
        hs[t + 256] = h[(size_t)b * HDIM + t + 256];
        __syncthreads();
        float acc0 = 0.f, acc1 = 0.f;
        for (int k = 0; k < HDIM; ++k) {
            float hv = hs[k];
            acc0 += hv * Ww[(size_t)k * ATT + t];
            acc1 += hv * Ww[(size_t)k * ATT + t + 256];
        }
        whp[(size_t)b * ATT + t]       = acc0 + Wb[t] + Ub[t];
        whp[(size_t)b * ATT + t + 256] = acc1 + Wb[t + 256] + Ub[t + 256];
    }
}

// ---------------------------------------------------------------------------
// Kernel G: 128x128 tile, BK=64, 4 waves. A = fp32 V, reg-staged with
// in-loop cvt (2-deep static pipeline, named reg buffers, peeled tail —
// zero guards in main body so the compiler's auto-waitcnt is exact);
// B = bf16 UwT via global_load_lds (XOR, pre-swizzled source). Two
// s_barriers per K-step; B(kt+2)/A(kt+2) stay in flight across them.
// Epilogue: e_part[cc][m] = sum_cols tanh(acc+whp)*vw.
// ---------------------------------------------------------------------------
__global__ __launch_bounds__(256, 2) void k_scores(
    const float* __restrict__ Vf, const __bf16* __restrict__ UwT,
    const float* __restrict__ whp, const float* __restrict__ vw,
    float* __restrict__ e_part)
{
    __shared__ __align__(16) __bf16 As[2][BM1][BKK];   // 32 KB
    __shared__ __align__(16) __bf16 Bs[2][BN1][BKK];   // 32 KB
    __shared__ float red[2][BM1];

    int bid = blockIdx.x;
    int lid = (bid & 7) * (784 / 8) + (bid >> 3);
    int mtile = lid >> 2;         // 0..195
    int cc    = lid & 3;          // 0..3
    int m0 = mtile * BM1;
    int c0 = cc * BN1;
    int t    = threadIdx.x;
    int lane = t & 63;
    int wave = t >> 6;
    int wr = wave >> 1;
    int wc = wave & 1;

    f32x4 acc[4][4];
#pragma unroll
    for (int i = 0; i < 4; ++i)
#pragma unroll
        for (int j = 0; j < 4; ++j) acc[i][j] = (f32x4){0.f, 0.f, 0.f, 0.f};

    // ---- B staging (gload_lds: linear dest, pre-swizzled source) ----
    int lr  = lane >> 3;
    int csw = ((lane & 7) ^ lr) * 8;
    const __bf16* BgS = UwT + (size_t)(c0 + wave * 32 + lr) * VDIM + csw;
    __bf16* Bl0 = &Bs[0][wave * 32 + lr][(lane & 7) * 8];

    // ---- A staging (fp32 reg load -> cvt -> XOR ds_write) ----
    int ra = t >> 1;              // 0..127 row
    const float* Af = Vf + (size_t)(m0 + ra) * VDIM + (t & 1) * 32;

    float4 aX[8], aY[8];          // named double buffer (static indices only)

#define B_GLOAD(buf, kt)                                                        \
    do {                                                                        \
        _Pragma("unroll")                                                       \
        for (int i = 0; i < 4; ++i)                                             \
            gload_lds16(BgS + (kt) * BKK + (size_t)i * 8 * VDIM,                \
                        Bl0 + (buf) * (BN1 * BKK) + i * 8 * BKK);               \
    } while (0)

#define A_LOAD(reg, kt)                                                         \
    do {                                                                        \
        const float4* src = reinterpret_cast<const float4*>(Af + (kt) * BKK);   \
        _Pragma("unroll")                                                       \
        for (int i = 0; i < 8; ++i) reg[i] = src[i];                            \
    } while (0)

#define A_CVT_WRITE(reg, buf)                                                   \
    do {                                                                        \
        _Pragma("unroll")                                                       \
        for (int i = 0; i < 4; ++i) {                                           \
            float4 x = reg[2 * i], y = reg[2 * i + 1];                          \
            bf16x8 w;                                                           \
            w[0] = (__bf16)x.x; w[1] = (__bf16)x.y;                             \
            w[2] = (__bf16)x.z; w[3] = (__bf16)x.w;                             \
            w[4] = (__bf16)y.x; w[5] = (__bf16)y.y;                             \
            w[6] = (__bf16)y.z; w[7] = (__bf16)y.w;                             \
            int ch = (((t & 1) * 4 + i) ^ (ra & 7)) * 8;                        \
            *reinterpret_cast<bf16x8*>(&As[buf][ra][ch]) = w;                   \
        }                                                                       \
    } while (0)

    int lcol = lane & 15;
    int lg4  = lane >> 4;
    int arow0 = wr * 64;
    int bcol0 = wc * 64;

#define MFMA_STEP(buf)                                                          \
    do {                                                                        \
        __builtin_amdgcn_sched_barrier(0);                                      \
        _Pragma("unroll")                                                       \
        for (int ks = 0; ks < 2; ++ks) {                                        \
            bf16x8 af[4], bfr[4];                                               \
            _Pragma("unroll")                                                   \
            for (int i = 0; i < 4; ++i) {                                       \
                int row = arow0 + i * 16 + lcol;                                \
                int ch  = ((ks * 4 + lg4) ^ (row & 7)) * 8;                     \
                af[i] = *reinterpret_cast<const bf16x8*>(&As[buf][row][ch]);    \
            }                                                                   \
            _Pragma("unroll")                                                   \
            for (int j = 0; j < 4; ++j) {                                       \
                int row = bcol0 + j * 16 + lcol;                                \
                int ch  = ((ks * 4 + lg4) ^ (row & 7)) * 8;                     \
                bfr[j] = *reinterpret_cast<const bf16x8*>(&Bs[buf][row][ch]);   \
            }                                                                   \
            __builtin_amdgcn_s_setprio(1);                                      \
            _Pragma("unroll")                                                   \
            for (int i = 0; i < 4; ++i)                                         \
                _Pragma("unroll")                                               \
                for (int j = 0; j < 4; ++j)                                     \
                    acc[i][j] = __builtin_amdgcn_mfma_f32_16x16x32_bf16(        \
                        af[i], bfr[j], acc[i][j], 0, 0, 0);                     \
            __builtin_amdgcn_s_setprio(0);                                      \
        }                                                                       \
        __builtin_amdgcn_sched_barrier(0);                                      \
    } while (0)

    // ---- prologue: tiles 0 and 1 ----
    B_GLOAD(0, 0);
    A_LOAD(aX, 0);
    A_CVT_WRITE(aX, 0);                 // auto-wait drains B(0)+A(0)
    B_GLOAD(1, 1);
    A_LOAD(aY, 1);
    asm volatile("s_waitcnt lgkmcnt(0)\n\ts_barrier" ::: "memory");

    // ---- main loop: kt = 0..NT-3, pairs (even buf=0, odd buf=1) ----
    // Per kt: MFMA(kt) | bar | issue B/A(kt+2) | cvt A(kt+1) | lgkm+bar.
    for (int ktp = 0; ktp < (NT - 2) / 2; ++ktp) {
        int kte = 2 * ktp;              // even kt, buf 0
        // --- kt even: reg[kt&1]=aX gets kt+2; cvt kt+1 from aY ---
        MFMA_STEP(0);
        asm volatile("s_barrier" ::: "memory");
        B_GLOAD(0, kte + 2);
        A_LOAD(aX, kte + 2);
        __builtin_amdgcn_sched_barrier(0);
        A_CVT_WRITE(aY, 1);             // A(kt+1) -> As[1]; auto vmcnt(12)
        asm volatile("s_waitcnt lgkmcnt(0)\n\ts_barrier" ::: "memory");
        // --- kt odd ---
        MFMA_STEP(1);
        asm volatile("s_barrier" ::: "memory");
        B_GLOAD(1, kte + 3);
        A_LOAD(aY, kte + 3);
        __builtin_amdgcn_sched_barrier(0);
        A_CVT_WRITE(aX, 0);             // A(kt+2) -> As[0]
        asm volatile("s_waitcnt lgkmcnt(0)\n\ts_barrier" ::: "memory");
    }

    // ---- tail kt = NT-2 (buf 0): no new issue; cvt A(NT-1) from aY ----
    MFMA_STEP(0);
    asm volatile("s_barrier" ::: "memory");
    A_CVT_WRITE(aY, 1);                 // auto-wait drains remaining loads
    asm volatile("s_waitcnt lgkmcnt(0)\n\ts_barrier" ::: "memory");
    // ---- tail kt = NT-1 (buf 1) ----
    MFMA_STEP(1);

#undef B_GLOAD
#undef A_LOAD
#undef A_CVT_WRITE
#undef MFMA_STEP

    // ---- epilogue: rowsum over this block's 128 cols ----
    int lrow4 = lg4 * 4;
#pragma unroll
    for (int i = 0; i < 4; ++i) {
        float rs[4] = {0.f, 0.f, 0.f, 0.f};
#pragma unroll
        for (int j = 0; j < 4; ++j) {
            int col = c0 + wc * 64 + j * 16 + lcol;
            float vwv = vw[col];
#pragma unroll
            for (int r = 0; r < 4; ++r) {
                int m = m0 + wr * 64 + i * 16 + lrow4 + r;
                int b = m / N_;
                float x = acc[i][j][r] + whp[(size_t)b * ATT + col];
                rs[r] += fast_tanh(x) * vwv;
            }
        }
#pragma unroll
        for (int r = 0; r < 4; ++r) {
            float v = rs[r];
            v += __shfl_xor(v, 1);
            v += __shfl_xor(v, 2);
            v += __shfl_xor(v, 4);
            v += __shfl_xor(v, 8);
            if (lcol == 0)
                red[wc][wr * 64 + i * 16 + lrow4 + r] = v;
        }
    }
    __syncthreads();
    if (t < BM1)
        e_part[(size_t)cc * M_TOT + m0 + t] = red[0][t] + red[1][t];
}

// ---------------------------------------------------------------------------
// Kernel S: softmax over N=196 per batch (4 partial score arrays)
// ---------------------------------------------------------------------------
__global__ void k_softmax(const float* __restrict__ e_part, const float* __restrict__ vb,
                          float* __restrict__ a_out) {
    int b = blockIdx.x;
    int t = threadIdx.x;  // 256
    __shared__ float sm[256];
    float ev = 0.f;
    float e  = -1e30f;
    if (t < N_) {
        int m = b * N_ + t;
        ev = e_part[m] + e_part[M_TOT + m] + e_part[2 * M_TOT + m] + e_part[3 * M_TOT + m] + vb[0];
        e = ev;
    }
    sm[t] = e;
    __syncthreads();
    for (int s = 128; s > 0; s >>= 1) {
        if (t < s) sm[t] = fmaxf(sm[t], sm[t + s]);
        __syncthreads();
    }
    float mx = sm[0];
    __syncthreads();
    float ex = (t < N_) ? __expf(ev - mx) : 0.f;
    sm[t] = ex;
    __syncthreads();
    for (int s = 128; s > 0; s >>= 1) {
        if (t < s) sm[t] += sm[t + s];
        __syncthreads();
    }
    float inv = 1.f / sm[0];
    if (t < N_) a_out[(size_t)b * N_ + t] = ex * inv;
}

// ---------------------------------------------------------------------------
// Kernel C: ctx[b][v] = sum_n a[b][n] * V[b][n][v]  (fp32 V, L3-warm)
// ---------------------------------------------------------------------------
__global__ void k_ctx_f32(const float* __restrict__ V, const float* __restrict__ a,
                          float* __restrict__ ctx) {
    int b  = blockIdx.x;
    int ch = blockIdx.y;
    int t  = threadIdx.x;  // 128
    __shared__ float as_[N_];
    for (int i = t; i < N_; i += 128) as_[i] = a[(size_t)b * N_ + i];
    __syncthreads();
    int col = ch * 512 + t * 4;
    const f32x4* Vp = reinterpret_cast<const f32x4*>(V + (size_t)b * N_ * VDIM + col);
    f32x4 accv = {0.f, 0.f, 0.f, 0.f};
    for (int n = 0; n < N_; ++n)
        accv += as_[n] * Vp[(size_t)n * (VDIM / 4)];
    *reinterpret_cast<f32x4*>(ctx + (size_t)b * VDIM + col) = accv;
}

// ---------------------------------------------------------------------------
extern "C" void kernel_launch(void* const* d_in, const int* in_sizes, int n_in,
                              void* d_out, int out_size, void* d_ws, size_t ws_size,
                              hipStream_t stream) {
    const float* h  = (const float*)d_in[0];
    const float* V  = (const float*)d_in[1];
    const float* Ww = (const float*)d_in[2];
    const float* Wb = (const float*)d_in[3];
    const float* Uw = (const float*)d_in[4];
    const float* Ub = (const float*)d_in[5];
    const float* vw = (const float*)d_in[6];
    const float* vb = (const float*)d_in[7];

    float* out     = (float*)d_out;
    float* ctx_out = out;                        // B*VDIM floats
    float* a_out   = out + (size_t)B_ * VDIM;    // B*N floats

    char*   ws    = (char*)d_ws;
    __bf16* UwT   = (__bf16*)ws;                                   // 2 MiB
    float*  whp   = (float*)(ws + 2u * 1024 * 1024);               // 256 KiB
    float*  e_prt = (float*)(ws + 2u * 1024 * 1024 + 256 * 1024);  // ~400 KiB

    k_prep<<<dim3(384), 256, 0, stream>>>(Uw, UwT, h, Ww, Wb, Ub, whp);
    k_scores<<<dim3(784), 256, 0, stream>>>(V, UwT, whp, vw, e_prt);
    k_softmax<<<dim3(B_), 256, 0, stream>>>(e_prt, vb, a_out);
    k_ctx_f32<<<dim3(B_, 4), 128, 0, stream>>>(V, a_out, ctx_out);
}

// Round 9
// 244.581 us; speedup vs baseline: 1.0178x; 1.0178x over previous
//
#include <hip/hip_runtime.h>
#include <hip/hip_bf16.h>

#define B_    128
#define N_    196
#define HDIM  512
#define VDIM  2048
#define ATT   512
#define M_TOT (B_ * N_)   // 25088

#define BKK 64             // K step (64 f32/bf16 elems)
#define NT  (VDIM / BKK)   // 32 K-steps
#define BM1 128
#define BN1 128

typedef float  f32x4  __attribute__((ext_vector_type(4)));
typedef __bf16 bf16x8 __attribute__((ext_vector_type(8)));

__device__ __forceinline__ void gload_lds16(const void* g, void* l) {
    __builtin_amdgcn_global_load_lds(
        (const __attribute__((address_space(1))) void*)g,
        (__attribute__((address_space(3))) void*)l, 16, 0, 0);
}

__device__ __forceinline__ float fast_tanh(float x) {
    float ax = fabsf(x);
    float e  = __expf(-2.f * ax);          // in (0,1], no overflow
    float t  = (1.f - e) / (1.f + e);
    return copysignf(t, x);
}

// ---------------------------------------------------------------------------
// Kernel P: blocks [0,256): Uw transpose -> UwT bf16; [256,384): whp.
// ---------------------------------------------------------------------------
__global__ void k_prep(const float* __restrict__ Uw, __bf16* __restrict__ UwT,
                       const float* __restrict__ h, const float* __restrict__ Ww,
                       const float* __restrict__ Wb, const float* __restrict__ Ub,
                       float* __restrict__ whp) {
    int t = threadIdx.x;  // 256
    if (blockIdx.x < 256) {
        __shared__ __bf16 st[64][65];
        int k0 = (blockIdx.x & 31) * 64;
        int c0 = (blockIdx.x >> 5) * 64;
#pragma unroll
        for (int i = 0; i < 16; ++i) {
            int lin = i * 256 + t;
            int kk = lin >> 6, cc = lin & 63;
            st[kk][cc] = (__bf16)Uw[(size_t)(k0 + kk) * ATT + c0 + cc];
        }
        __syncthreads();
#pragma unroll
        for (int i = 0; i < 16; ++i) {
            int lin = i * 256 + t;
            int cc = lin >> 6, kk = lin & 63;
            UwT[(size_t)(c0 + cc) * VDIM + k0 + kk] = st[kk][cc];
        }
    } else {
        __shared__ float hs[HDIM];
        int b = blockIdx.x - 256;
        hs[t]       = h[(size_t)b * HDIM + t];
        hs[t + 256] = h[(size_t)b * HDIM + t + 256];
        __syncthreads();
        float acc0 = 0.f, acc1 = 0.f;
        for (int k = 0; k < HDIM; ++k) {
            float hv = hs[k];
            acc0 += hv * Ww[(size_t)k * ATT + t];
            acc1 += hv * Ww[(size_t)k * ATT + t + 256];
        }
        whp[(size_t)b * ATT + t]       = acc0 + Wb[t] + Ub[t];
        whp[(size_t)b * ATT + t + 256] = acc1 + Wb[t + 256] + Ub[t + 256];
    }
}

// ---------------------------------------------------------------------------
// Kernel G: 128x128 tile, BK=64, 4 waves. A staged as FP32 via
// global_load_lds (no conversion pass!); fp32->bf16 cvt happens on the
// LDS->reg fragment read. B = bf16 UwT via global_load_lds. Both XOR-
// swizzled (pre-swizzled per-lane source, linear dest, swizzled ds_read):
//   A: 16 chunks/row,  LDS[r][c] holds global chunk c^(r&7)
//   B:  8 chunks/row,  LDS[r][c] holds global chunk c^(r&7)
// Counted-vmcnt 2-deep pipeline (12 loads/STAGE -> wait vmcnt(12)).
// LDS = 97 KB -> 1 block/CU. Grid 784, XCD-bijective swizzle.
// Epilogue: e_part[cc][m] = sum_cols tanh(acc+whp)*vw.
// ---------------------------------------------------------------------------
__global__ __launch_bounds__(256, 1) void k_scores(
    const float* __restrict__ Vf, const __bf16* __restrict__ UwT,
    const float* __restrict__ whp, const float* __restrict__ vw,
    float* __restrict__ e_part)
{
    __shared__ __align__(16) float  As[2][BM1][BKK];   // 64 KB (fp32!)
    __shared__ __align__(16) __bf16 Bs[2][BN1][BKK];   // 32 KB
    __shared__ float red[2][BM1];                      // 1 KB

    int bid = blockIdx.x;
    int lid = (bid & 7) * (784 / 8) + (bid >> 3);
    int mtile = lid >> 2;         // 0..195
    int cc    = lid & 3;          // 0..3
    int m0 = mtile * BM1;
    int c0 = cc * BN1;
    int t    = threadIdx.x;
    int lane = t & 63;
    int wave = t >> 6;
    int wr = wave >> 1;
    int wc = wave & 1;

    f32x4 acc[4][4];
#pragma unroll
    for (int i = 0; i < 4; ++i)
#pragma unroll
        for (int j = 0; j < 4; ++j) acc[i][j] = (f32x4){0.f, 0.f, 0.f, 0.f};

    // ---- B staging (as R7): wave w instr i covers rows w*32+i*8..+8 ----
    int lr8 = lane >> 3;                          // 0..7
    int csB = ((lane & 7) ^ lr8) * 8;             // pre-swizzled source elems
    const __bf16* BgS = UwT + (size_t)(c0 + wave * 32 + lr8) * VDIM + csB;
    __bf16* Bl0 = &Bs[0][wave * 32 + lr8][(lane & 7) * 8];

    // ---- A staging (fp32): wave w instr i covers rows w*32+i*4..+4 ----
    // lane l -> row_in_instr = l>>4, chunk c = l&15 (16B chunks of 16 per row)
    // LDS[r][c] holds global chunk c ^ (r&7); r&7 = (i*4 + (l>>4)) & 7
    //   even i: g = (l&15) ^ (l>>4)          odd i: g = g_even ^ 4
    int hl = lane >> 4;                           // 0..3
    int gE = (lane & 15) ^ hl;                    // even-instr global chunk
    int gO = gE ^ 4;                              // odd-instr global chunk
    const float* AgE = Vf + (size_t)(m0 + wave * 32 + hl) * VDIM + gE * 4;
    const float* AgO = Vf + (size_t)(m0 + wave * 32 + 4 + hl) * VDIM + gO * 4;
    float* Al0 = &As[0][wave * 32][0];            // + i*1024B; lane*16 auto

    // 12 gloads per STAGE (8 A + 4 B) -> vmcnt(12) == one STAGE outstanding
#define STAGE(buf, kt)                                                          \
    do {                                                                        \
        _Pragma("unroll")                                                       \
        for (int i = 0; i < 4; ++i)                                             \
            gload_lds16(BgS + (kt) * BKK + (size_t)i * 8 * VDIM,                \
                        Bl0 + (buf) * (BN1 * BKK) + i * 8 * BKK);               \
        _Pragma("unroll")                                                       \
        for (int j = 0; j < 4; ++j) {                                           \
            gload_lds16(AgE + (kt) * BKK + (size_t)j * 8 * VDIM,                \
                        Al0 + (buf) * (BM1 * BKK) + (2 * j) * 4 * BKK);         \
            gload_lds16(AgO + (kt) * BKK + (size_t)j * 8 * VDIM,                \
                        Al0 + (buf) * (BM1 * BKK) + (2 * j + 1) * 4 * BKK);     \
        }                                                                       \
    } while (0)

    int lcol = lane & 15;
    int lg4  = lane >> 4;
    int arow0 = wr * 64;
    int bcol0 = wc * 64;

    STAGE(0, 0);
    __builtin_amdgcn_sched_barrier(0);
    STAGE(1, 1);

    for (int kt = 0; kt < NT; ++kt) {
        int buf = kt & 1;
        if (kt < NT - 1) {
            asm volatile("s_waitcnt vmcnt(12)\n\ts_barrier" ::: "memory");
        } else {
            asm volatile("s_waitcnt vmcnt(0)\n\ts_barrier" ::: "memory");
        }
        __builtin_amdgcn_sched_barrier(0);

#pragma unroll
        for (int ks = 0; ks < 2; ++ks) {
            bf16x8 af[4], bfr[4];
#pragma unroll
            for (int i = 0; i < 4; ++i) {
                int row = arow0 + i * 16 + lcol;
                int q   = ks * 4 + lg4;                 // 0..7 (8-f32 group)
                int c0i = (2 * q) ^ (row & 7);          // LDS chunk of elems 0-3
                int c1i = c0i ^ 1;                      // LDS chunk of elems 4-7
                f32x4 lo = *reinterpret_cast<const f32x4*>(&As[buf][row][c0i * 4]);
                f32x4 hi = *reinterpret_cast<const f32x4*>(&As[buf][row][c1i * 4]);
                bf16x8 w;
                w[0] = (__bf16)lo.x; w[1] = (__bf16)lo.y;
                w[2] = (__bf16)lo.z; w[3] = (__bf16)lo.w;
                w[4] = (__bf16)hi.x; w[5] = (__bf16)hi.y;
                w[6] = (__bf16)hi.z; w[7] = (__bf16)hi.w;
                af[i] = w;
            }
#pragma unroll
            for (int j = 0; j < 4; ++j) {
                int row = bcol0 + j * 16 + lcol;
                int ch  = ((ks * 4 + lg4) ^ (row & 7)) * 8;
                bfr[j] = *reinterpret_cast<const bf16x8*>(&Bs[buf][row][ch]);
            }
            __builtin_amdgcn_s_setprio(1);
#pragma unroll
            for (int i = 0; i < 4; ++i)
#pragma unroll
                for (int j = 0; j < 4; ++j)
                    acc[i][j] = __builtin_amdgcn_mfma_f32_16x16x32_bf16(af[i], bfr[j], acc[i][j], 0, 0, 0);
            __builtin_amdgcn_s_setprio(0);
        }

        __builtin_amdgcn_sched_barrier(0);
        asm volatile("s_barrier" ::: "memory");   // buf free: all waves consumed it
        if (kt + 2 < NT) STAGE(buf, kt + 2);
    }
#undef STAGE

    // ---- epilogue: rowsum over this block's 128 cols ----
    int lrow4 = lg4 * 4;
#pragma unroll
    for (int i = 0; i < 4; ++i) {
        float rs[4] = {0.f, 0.f, 0.f, 0.f};
#pragma unroll
        for (int j = 0; j < 4; ++j) {
            int col = c0 + wc * 64 + j * 16 + lcol;
            float vwv = vw[col];
#pragma unroll
            for (int r = 0; r < 4; ++r) {
                int m = m0 + wr * 64 + i * 16 + lrow4 + r;
                int b = m / N_;
                float x = acc[i][j][r] + whp[(size_t)b * ATT + col];
                rs[r] += fast_tanh(x) * vwv;
            }
        }
#pragma unroll
        for (int r = 0; r < 4; ++r) {
            float v = rs[r];
            v += __shfl_xor(v, 1);
            v += __shfl_xor(v, 2);
            v += __shfl_xor(v, 4);
            v += __shfl_xor(v, 8);
            if (lcol == 0)
                red[wc][wr * 64 + i * 16 + lrow4 + r] = v;
        }
    }
    __syncthreads();
    if (t < BM1)
        e_part[(size_t)cc * M_TOT + m0 + t] = red[0][t] + red[1][t];
}

// ---------------------------------------------------------------------------
// Kernel S: softmax over N=196 per batch (4 partial score arrays)
// ---------------------------------------------------------------------------
__global__ void k_softmax(const float* __restrict__ e_part, const float* __restrict__ vb,
                          float* __restrict__ a_out) {
    int b = blockIdx.x;
    int t = threadIdx.x;  // 256
    __shared__ float sm[256];
    float ev = 0.f;
    float e  = -1e30f;
    if (t < N_) {
        int m = b * N_ + t;
        ev = e_part[m] + e_part[M_TOT + m] + e_part[2 * M_TOT + m] + e_part[3 * M_TOT + m] + vb[0];
        e = ev;
    }
    sm[t] = e;
    __syncthreads();
    for (int s = 128; s > 0; s >>= 1) {
        if (t < s) sm[t] = fmaxf(sm[t], sm[t + s]);
        __syncthreads();
    }
    float mx = sm[0];
    __syncthreads();
    float ex = (t < N_) ? __expf(ev - mx) : 0.f;
    sm[t] = ex;
    __syncthreads();
    for (int s = 128; s > 0; s >>= 1) {
        if (t < s) sm[t] += sm[t + s];
        __syncthreads();
    }
    float inv = 1.f / sm[0];
    if (t < N_) a_out[(size_t)b * N_ + t] = ex * inv;
}

// ---------------------------------------------------------------------------
// Kernel C: ctx[b][v] = sum_n a[b][n] * V[b][n][v]  (fp32 V, L3-warm)
// ---------------------------------------------------------------------------
__global__ void k_ctx_f32(const float* __restrict__ V, const float* __restrict__ a,
                          float* __restrict__ ctx) {
    int b  = blockIdx.x;
    int ch = blockIdx.y;
    int t  = threadIdx.x;  // 128
    __shared__ float as_[N_];
    for (int i = t; i < N_; i += 128) as_[i] = a[(size_t)b * N_ + i];
    __syncthreads();
    int col = ch * 512 + t * 4;
    const f32x4* Vp = reinterpret_cast<const f32x4*>(V + (size_t)b * N_ * VDIM + col);
    f32x4 accv = {0.f, 0.f, 0.f, 0.f};
    for (int n = 0; n < N_; ++n)
        accv += as_[n] * Vp[(size_t)n * (VDIM / 4)];
    *reinterpret_cast<f32x4*>(ctx + (size_t)b * VDIM + col) = accv;
}

// ---------------------------------------------------------------------------
extern "C" void kernel_launch(void* const* d_in, const int* in_sizes, int n_in,
                              void* d_out, int out_size, void* d_ws, size_t ws_size,
                              hipStream_t stream) {
    const float* h  = (const float*)d_in[0];
    const float* V  = (const float*)d_in[1];
    const float* Ww = (const float*)d_in[2];
    const float* Wb = (const float*)d_in[3];
    const float* Uw = (const float*)d_in[4];
    const float* Ub = (const float*)d_in[5];
    const float* vw = (const float*)d_in[6];
    const float* vb = (const float*)d_in[7];

    float* out     = (float*)d_out;
    float* ctx_out = out;                        // B*VDIM floats
    float* a_out   = out + (size_t)B_ * VDIM;    // B*N floats

    char*   ws    = (char*)d_ws;
    __bf16* UwT   = (__bf16*)ws;                                   // 2 MiB
    float*  whp   = (float*)(ws + 2u * 1024 * 1024);               // 256 KiB
    float*  e_prt = (float*)(ws + 2u * 1024 * 1024 + 256 * 1024);  // ~400 KiB

    k_prep<<<dim3(384), 256, 0, stream>>>(Uw, UwT, h, Ww, Wb, Ub, whp);
    k_scores<<<dim3(784), 256, 0, stream>>>(V, UwT, whp, vw, e_prt);
    k_softmax<<<dim3(B_), 256, 0, stream>>>(e_prt, vb, a_out);
    k_ctx_f32<<<dim3(B_, 4), 128, 0, stream>>>(V, a_out, ctx_out);
}

// Round 10
// 160.374 us; speedup vs baseline: 1.5523x; 1.5251x over previous
//
#include <hip/hip_runtime.h>
#include <hip/hip_bf16.h>

#define B_    128
#define N_    196
#define HDIM  512
#define VDIM  2048
#define ATT   512
#define M_TOT (B_ * N_)   // 25088

#define BKK 64             // K step (64 bf16 = 128B = 8 chunks of 16B)
#define NT  (VDIM / BKK)   // 32 K-steps
#define BM1 128
#define BN1 128
#define N8     ((B_ * N_ * VDIM) / 8)   // 6,422,528 float8 items
#define NCONVB 3136                      // conv blocks (grid-stride x8)

typedef float  f32x4  __attribute__((ext_vector_type(4)));
typedef __bf16 bf16x8 __attribute__((ext_vector_type(8)));

__device__ __forceinline__ void gload_lds16(const void* g, void* l) {
    __builtin_amdgcn_global_load_lds(
        (const __attribute__((address_space(1))) void*)g,
        (__attribute__((address_space(3))) void*)l, 16, 0, 0);
}

__device__ __forceinline__ float fast_tanh(float x) {
    float ax = fabsf(x);
    float e  = __expf(-2.f * ax);          // in (0,1], no overflow
    float t  = (1.f - e) / (1.f + e);
    return copysignf(t, x);
}

// ---------------------------------------------------------------------------
// Kernel CP (merged, prep FIRST so the long-pole wh blocks overlap conv):
//   [0,128):           whp = h@Ww + Wb + Ub       (long: 512-iter dots)
//   [128,384):         Uw transpose -> UwT bf16
//   [384,384+convb):   V fp32 -> bf16 (grid-stride over N8)
// ---------------------------------------------------------------------------
__global__ void k_convprep(const float* __restrict__ V, __bf16* __restrict__ Vb,
                           const float* __restrict__ Uw, __bf16* __restrict__ UwT,
                           const float* __restrict__ h, const float* __restrict__ Ww,
                           const float* __restrict__ Wb, const float* __restrict__ Ub,
                           float* __restrict__ whp, int conv_blocks) {
    int t = threadIdx.x;  // 256
    if (blockIdx.x < 128) {
        __shared__ float hs[HDIM];
        int b = blockIdx.x;
        hs[t]       = h[(size_t)b * HDIM + t];
        hs[t + 256] = h[(size_t)b * HDIM + t + 256];
        __syncthreads();
        float acc0 = 0.f, acc1 = 0.f;
        for (int k = 0; k < HDIM; ++k) {
            float hv = hs[k];
            acc0 += hv * Ww[(size_t)k * ATT + t];
            acc1 += hv * Ww[(size_t)k * ATT + t + 256];
        }
        whp[(size_t)b * ATT + t]       = acc0 + Wb[t] + Ub[t];
        whp[(size_t)b * ATT + t + 256] = acc1 + Wb[t + 256] + Ub[t + 256];
    } else if (blockIdx.x < 384) {
        __shared__ __bf16 st[64][65];
        int bb = blockIdx.x - 128;
        int k0 = (bb & 31) * 64;
        int c0 = (bb >> 5) * 64;
#pragma unroll
        for (int i = 0; i < 16; ++i) {
            int lin = i * 256 + t;
            int kk = lin >> 6, cc = lin & 63;
            st[kk][cc] = (__bf16)Uw[(size_t)(k0 + kk) * ATT + c0 + cc];
        }
        __syncthreads();
#pragma unroll
        for (int i = 0; i < 16; ++i) {
            int lin = i * 256 + t;
            int cc = lin >> 6, kk = lin & 63;
            UwT[(size_t)(c0 + cc) * VDIM + k0 + kk] = st[kk][cc];
        }
    } else {
        int cb = blockIdx.x - 384;           // 0..conv_blocks-1
        int stride = conv_blocks * 256;
        for (int i = cb * 256 + t; i < N8; i += stride) {
            const float4* s = reinterpret_cast<const float4*>(V + (size_t)i * 8);
            float4 x = s[0], y = s[1];
            bf16x8 w;
            w[0] = (__bf16)x.x; w[1] = (__bf16)x.y; w[2] = (__bf16)x.z; w[3] = (__bf16)x.w;
            w[4] = (__bf16)y.x; w[5] = (__bf16)y.y; w[6] = (__bf16)y.z; w[7] = (__bf16)y.w;
            reinterpret_cast<bf16x8*>(Vb)[i] = w;
        }
    }
}

// ---------------------------------------------------------------------------
// Kernel G (main): 128x128 tile, BK=64, 4 waves, double-buffered with
// COUNTED vmcnt pipeline (depth 2): tile kt+1's 8 gload_lds stay in flight
// across tile kt's compute; waits vmcnt(8), drains to 0 only on the last
// iteration. Both operands XOR-swizzled (pre-swizzled source, linear
// gload_lds dest, swizzled ds_read). 784 blocks (XCD-bijective), 2/CU.
// [R7-verified: passed, absmax 0.00195, ~22-40us]
// ---------------------------------------------------------------------------
__global__ __launch_bounds__(256, 2) void k_scores128(
    const __bf16* __restrict__ Vb, const __bf16* __restrict__ UwT,
    const float* __restrict__ whp, const float* __restrict__ vw,
    float* __restrict__ e_part)
{
    __shared__ __align__(16) __bf16 As[2][BM1][BKK];   // 32 KB
    __shared__ __align__(16) __bf16 Bs[2][BN1][BKK];   // 32 KB
    __shared__ float red[2][BM1];

    int bid = blockIdx.x;
    int lid = (bid & 7) * (784 / 8) + (bid >> 3);
    int mtile = lid >> 2;         // 0..195
    int cc    = lid & 3;          // 0..3
    int m0 = mtile * BM1;
    int c0 = cc * BN1;
    int t    = threadIdx.x;
    int lane = t & 63;
    int wave = t >> 6;
    int wr = wave >> 1;
    int wc = wave & 1;

    f32x4 acc[4][4];
#pragma unroll
    for (int i = 0; i < 4; ++i)
#pragma unroll
        for (int j = 0; j < 4; ++j) acc[i][j] = (f32x4){0.f, 0.f, 0.f, 0.f};

    int lr  = lane >> 3;
    int csw = ((lane & 7) ^ lr) * 8;
    const __bf16* AgS = Vb  + (size_t)(m0 + wave * 32 + lr) * VDIM + csw;
    const __bf16* BgS = UwT + (size_t)(c0 + wave * 32 + lr) * VDIM + csw;
    __bf16* Al0 = &As[0][wave * 32 + lr][(lane & 7) * 8];
    __bf16* Bl0 = &Bs[0][wave * 32 + lr][(lane & 7) * 8];

#define STAGE(buf, kt)                                                          \
    do {                                                                        \
        _Pragma("unroll")                                                       \
        for (int i = 0; i < 4; ++i) {                                           \
            gload_lds16(AgS + (kt) * BKK + (size_t)i * 8 * VDIM,                \
                        Al0 + (buf) * (BM1 * BKK) + i * 8 * BKK);               \
            gload_lds16(BgS + (kt) * BKK + (size_t)i * 8 * VDIM,                \
                        Bl0 + (buf) * (BN1 * BKK) + i * 8 * BKK);               \
        }                                                                       \
    } while (0)

    int lcol = lane & 15;
    int lg4  = lane >> 4;
    int arow0 = wr * 64;
    int bcol0 = wc * 64;

    STAGE(0, 0);
    __builtin_amdgcn_sched_barrier(0);   // pin issue order: tile0 before tile1
    STAGE(1, 1);

    for (int kt = 0; kt < NT; ++kt) {
        int buf = kt & 1;
        if (kt < NT - 1) {
            asm volatile("s_waitcnt vmcnt(8)\n\ts_barrier" ::: "memory");
        } else {
            asm volatile("s_waitcnt vmcnt(0)\n\ts_barrier" ::: "memory");
        }
        __builtin_amdgcn_sched_barrier(0);

#pragma unroll
        for (int ks = 0; ks < 2; ++ks) {
            bf16x8 af[4], bfr[4];
#pragma unroll
            for (int i = 0; i < 4; ++i) {
                int row = arow0 + i * 16 + lcol;
                int ch  = ((ks * 4 + lg4) ^ (row & 7)) * 8;
                af[i] = *reinterpret_cast<const bf16x8*>(&As[buf][row][ch]);
            }
#pragma unroll
            for (int j = 0; j < 4; ++j) {
                int row = bcol0 + j * 16 + lcol;
                int ch  = ((ks * 4 + lg4) ^ (row & 7)) * 8;
                bfr[j] = *reinterpret_cast<const bf16x8*>(&Bs[buf][row][ch]);
            }
            __builtin_amdgcn_s_setprio(1);
#pragma unroll
            for (int i = 0; i < 4; ++i)
#pragma unroll
                for (int j = 0; j < 4; ++j)
                    acc[i][j] = __builtin_amdgcn_mfma_f32_16x16x32_bf16(af[i], bfr[j], acc[i][j], 0, 0, 0);
            __builtin_amdgcn_s_setprio(0);
        }

        __builtin_amdgcn_sched_barrier(0);
        asm volatile("s_barrier" ::: "memory");   // buf free: all waves consumed it
        if (kt + 2 < NT) STAGE(buf, kt + 2);
    }
#undef STAGE

    // ---- epilogue: rowsum over this block's 128 cols ----
    int lrow4 = lg4 * 4;
#pragma unroll
    for (int i = 0; i < 4; ++i) {
        float rs[4] = {0.f, 0.f, 0.f, 0.f};
#pragma unroll
        for (int j = 0; j < 4; ++j) {
            int col = c0 + wc * 64 + j * 16 + lcol;
            float vwv = vw[col];
#pragma unroll
            for (int r = 0; r < 4; ++r) {
                int m = m0 + wr * 64 + i * 16 + lrow4 + r;
                int b = m / N_;
                float x = acc[i][j][r] + whp[(size_t)b * ATT + col];
                rs[r] += fast_tanh(x) * vwv;
            }
        }
#pragma unroll
        for (int r = 0; r < 4; ++r) {
            float v = rs[r];
            v += __shfl_xor(v, 1);
            v += __shfl_xor(v, 2);
            v += __shfl_xor(v, 4);
            v += __shfl_xor(v, 8);
            if (lcol == 0)
                red[wc][wr * 64 + i * 16 + lrow4 + r] = v;
        }
    }
    __syncthreads();
    if (t < BM1)
        e_part[(size_t)cc * M_TOT + m0 + t] = red[0][t] + red[1][t];
}

// ---------------------------------------------------------------------------
// Kernel G (fallback, no-ws path): 128x128, fp32 A reg-staged, classic
// 2-phase drain barriers (R3-proven).
// ---------------------------------------------------------------------------
__global__ __launch_bounds__(256, 2) void k_scores_small(
    const float* __restrict__ Vf, const __bf16* __restrict__ UwT,
    const float* __restrict__ whp, const float* __restrict__ vw,
    float* __restrict__ e_part)
{
    __shared__ __align__(16) __bf16 As[2][BM1][BKK];
    __shared__ __align__(16) __bf16 Bs[2][BN1][BKK];
    __shared__ float red[2][BM1];

    int bid = blockIdx.x;
    int lid = (bid & 7) * (784 / 8) + (bid >> 3);
    int mtile = lid >> 2;
    int cc    = lid & 3;
    int m0 = mtile * BM1;
    int c0 = cc * BN1;
    int t    = threadIdx.x;
    int lane = t & 63;
    int wave = t >> 6;
    int wr = wave >> 1;
    int wc = wave & 1;

    f32x4 acc[4][4];
#pragma unroll
    for (int i = 0; i < 4; ++i)
#pragma unroll
        for (int j = 0; j < 4; ++j) acc[i][j] = (f32x4){0.f, 0.f, 0.f, 0.f};

    int lr  = lane >> 3;
    int csw = ((lane & 7) ^ lr) * 8;
    const __bf16* BgS = UwT + (size_t)(c0 + wave * 32 + lr) * VDIM + csw;
    __bf16* Bl0 = &Bs[0][wave * 32 + lr][(lane & 7) * 8];

    int ra = t >> 1;
    int ka = (t & 1) * 32;
    const float* Af = Vf + (size_t)(m0 + ra) * VDIM + ka;

#define STAGE1(buf, kt)                                                         \
    do {                                                                        \
        _Pragma("unroll")                                                       \
        for (int i = 0; i < 4; ++i)                                             \
            gload_lds16(BgS + (kt) * BKK + (size_t)i * 8 * VDIM,                \
                        Bl0 + (buf) * (BN1 * BKK) + i * 8 * BKK);               \
        const float4* src = reinterpret_cast<const float4*>(Af + (kt) * BKK);   \
        _Pragma("unroll")                                                       \
        for (int i = 0; i < 4; ++i) {                                           \
            float4 x = src[2 * i];                                              \
            float4 y = src[2 * i + 1];                                          \
            bf16x8 w;                                                           \
            w[0] = (__bf16)x.x; w[1] = (__bf16)x.y;                             \
            w[2] = (__bf16)x.z; w[3] = (__bf16)x.w;                             \
            w[4] = (__bf16)y.x; w[5] = (__bf16)y.y;                             \
            w[6] = (__bf16)y.z; w[7] = (__bf16)y.w;                             \
            int ch = (((t & 1) * 4 + i) ^ (ra & 7)) * 8;                        \
            *reinterpret_cast<bf16x8*>(&As[buf][ra][ch]) = w;                   \
        }                                                                       \
    } while (0)

    int lcol = lane & 15;
    int lg4  = lane >> 4;
    int arow0 = wr * 64;
    int bcol0 = wc * 64;

    STAGE1(0, 0);
    __syncthreads();

    for (int kt = 0; kt < NT; ++kt) {
        int buf = kt & 1;
        if (kt + 1 < NT) STAGE1(buf ^ 1, kt + 1);
#pragma unroll
        for (int ks = 0; ks < 2; ++ks) {
            bf16x8 af[4], bfr[4];
#pragma unroll
            for (int i = 0; i < 4; ++i) {
                int row = arow0 + i * 16 + lcol;
                int ch  = ((ks * 4 + lg4) ^ (row & 7)) * 8;
                af[i] = *reinterpret_cast<const bf16x8*>(&As[buf][row][ch]);
            }
#pragma unroll
            for (int j = 0; j < 4; ++j) {
                int row = bcol0 + j * 16 + lcol;
                int ch  = ((ks * 4 + lg4) ^ (row & 7)) * 8;
                bfr[j] = *reinterpret_cast<const bf16x8*>(&Bs[buf][row][ch]);
            }
#pragma unroll
            for (int i = 0; i < 4; ++i)
#pragma unroll
                for (int j = 0; j < 4; ++j)
                    acc[i][j] = __builtin_amdgcn_mfma_f32_16x16x32_bf16(af[i], bfr[j], acc[i][j], 0, 0, 0);
        }
        __syncthreads();
    }
#undef STAGE1

    int lrow4 = lg4 * 4;
#pragma unroll
    for (int i = 0; i < 4; ++i) {
        float rs[4] = {0.f, 0.f, 0.f, 0.f};
#pragma unroll
        for (int j = 0; j < 4; ++j) {
            int col = c0 + wc * 64 + j * 16 + lcol;
            float vwv = vw[col];
#pragma unroll
            for (int r = 0; r < 4; ++r) {
                int m = m0 + wr * 64 + i * 16 + lrow4 + r;
                int b = m / N_;
                float x = acc[i][j][r] + whp[(size_t)b * ATT + col];
                rs[r] += fast_tanh(x) * vwv;
            }
        }
#pragma unroll
        for (int r = 0; r < 4; ++r) {
            float v = rs[r];
            v += __shfl_xor(v, 1);
            v += __shfl_xor(v, 2);
            v += __shfl_xor(v, 4);
            v += __shfl_xor(v, 8);
            if (lcol == 0)
                red[wc][wr * 64 + i * 16 + lrow4 + r] = v;
        }
    }
    __syncthreads();
    if (t < BM1)
        e_part[(size_t)cc * M_TOT + m0 + t] = red[0][t] + red[1][t];
}

// ---------------------------------------------------------------------------
// Kernel S: softmax over N=196 per batch (4 partial score arrays)
// ---------------------------------------------------------------------------
__global__ void k_softmax(const float* __restrict__ e_part, const float* __restrict__ vb,
                          float* __restrict__ a_out) {
    int b = blockIdx.x;
    int t = threadIdx.x;  // 256
    __shared__ float sm[256];
    float ev = 0.f;
    float e  = -1e30f;
    if (t < N_) {
        int m = b * N_ + t;
        ev = e_part[m] + e_part[M_TOT + m] + e_part[2 * M_TOT + m] + e_part[3 * M_TOT + m] + vb[0];
        e = ev;
    }
    sm[t] = e;
    __syncthreads();
    for (int s = 128; s > 0; s >>= 1) {
        if (t < s) sm[t] = fmaxf(sm[t], sm[t + s]);
        __syncthreads();
    }
    float mx = sm[0];
    __syncthreads();
    float ex = (t < N_) ? __expf(ev - mx) : 0.f;
    sm[t] = ex;
    __syncthreads();
    for (int s = 128; s > 0; s >>= 1) {
        if (t < s) sm[t] += sm[t + s];
        __syncthreads();
    }
    float inv = 1.f / sm[0];
    if (t < N_) a_out[(size_t)b * N_ + t] = ex * inv;
}

// ---------------------------------------------------------------------------
// Kernel C: ctx[b][v] = sum_n a[b][n] * V[b][n][v]
// ---------------------------------------------------------------------------
__global__ void k_ctx_bf(const __bf16* __restrict__ Vb, const float* __restrict__ a,
                         float* __restrict__ ctx) {
    int b  = blockIdx.x;   // 128
    int ch = blockIdx.y;   // 2 chunks of 1024 cols
    int t  = threadIdx.x;  // 128
    __shared__ float as_[N_];
    for (int i = t; i < N_; i += 128) as_[i] = a[(size_t)b * N_ + i];
    __syncthreads();
    int col = ch * 1024 + t * 8;
    const __bf16* Vp = Vb + (size_t)b * N_ * VDIM + col;
    float av[8] = {0.f, 0.f, 0.f, 0.f, 0.f, 0.f, 0.f, 0.f};
    for (int n = 0; n < N_; ++n) {
        bf16x8 v = *reinterpret_cast<const bf16x8*>(Vp + (size_t)n * VDIM);
        float an = as_[n];
#pragma unroll
        for (int j = 0; j < 8; ++j) av[j] += an * (float)v[j];
    }
    f32x4 lo = {av[0], av[1], av[2], av[3]};
    f32x4 hi = {av[4], av[5], av[6], av[7]};
    f32x4* dst = reinterpret_cast<f32x4*>(ctx + (size_t)b * VDIM + col);
    dst[0] = lo;
    dst[1] = hi;
}

__global__ void k_ctx_f32(const float* __restrict__ V, const float* __restrict__ a,
                          float* __restrict__ ctx) {
    int b  = blockIdx.x;
    int ch = blockIdx.y;
    int t  = threadIdx.x;  // 128
    __shared__ float as_[N_];
    for (int i = t; i < N_; i += 128) as_[i] = a[(size_t)b * N_ + i];
    __syncthreads();
    int col = ch * 512 + t * 4;
    const f32x4* Vp = reinterpret_cast<const f32x4*>(V + (size_t)b * N_ * VDIM + col);
    f32x4 accv = {0.f, 0.f, 0.f, 0.f};
    for (int n = 0; n < N_; ++n)
        accv += as_[n] * Vp[(size_t)n * (VDIM / 4)];
    *reinterpret_cast<f32x4*>(ctx + (size_t)b * VDIM + col) = accv;
}

// ---------------------------------------------------------------------------
extern "C" void kernel_launch(void* const* d_in, const int* in_sizes, int n_in,
                              void* d_out, int out_size, void* d_ws, size_t ws_size,
                              hipStream_t stream) {
    const float* h  = (const float*)d_in[0];
    const float* V  = (const float*)d_in[1];
    const float* Ww = (const float*)d_in[2];
    const float* Wb = (const float*)d_in[3];
    const float* Uw = (const float*)d_in[4];
    const float* Ub = (const float*)d_in[5];
    const float* vw = (const float*)d_in[6];
    const float* vb = (const float*)d_in[7];

    float* out     = (float*)d_out;
    float* ctx_out = out;                        // B*VDIM floats
    float* a_out   = out + (size_t)B_ * VDIM;    // B*N floats

    const size_t vb_bytes = (size_t)B_ * N_ * VDIM * sizeof(__bf16);  // ~103 MB
    const size_t tail     = 2u * 1024 * 1024 + 256 * 1024 + (size_t)4 * M_TOT * 4 + 4096;
    bool preconv = ws_size >= vb_bytes + tail;

    char*   ws   = (char*)d_ws;
    __bf16* Vb   = (__bf16*)ws;
    char*   rest = ws + (preconv ? vb_bytes : 0);
    __bf16* UwT   = (__bf16*)rest;
    float*  whp   = (float*)(rest + 2u * 1024 * 1024);
    float*  e_prt = (float*)(rest + 2u * 1024 * 1024 + 256 * 1024);

    int conv_blocks = preconv ? NCONVB : 0;
    k_convprep<<<dim3(384 + conv_blocks), 256, 0, stream>>>(
        V, Vb, Uw, UwT, h, Ww, Wb, Ub, whp, conv_blocks);
    if (preconv) {
        k_scores128<<<dim3(784), 256, 0, stream>>>(Vb, UwT, whp, vw, e_prt);
        k_softmax<<<dim3(B_), 256, 0, stream>>>(e_prt, vb, a_out);
        k_ctx_bf<<<dim3(B_, 2), 128, 0, stream>>>(Vb, a_out, ctx_out);
    } else {
        k_scores_small<<<dim3(784), 256, 0, stream>>>(V, UwT, whp, vw, e_prt);
        k_softmax<<<dim3(B_), 256, 0, stream>>>(e_prt, vb, a_out);
        k_ctx_f32<<<dim3(B_, 4), 128, 0, stream>>>(V, a_out, ctx_out);
    }
}

// Round 11
// 152.272 us; speedup vs baseline: 1.6349x; 1.0532x over previous
//
#include <hip/hip_runtime.h>
#include <hip/hip_bf16.h>

#define B_    128
#define N_    196
#define HDIM  512
#define VDIM  2048
#define ATT   512
#define M_TOT (B_ * N_)   // 25088

#define BKK 64             // K step (64 bf16 = 128B = 8 chunks of 16B)
#define NT  (VDIM / BKK)   // 32 K-steps
#define BM1 128
#define BN1 128
#define N8     ((B_ * N_ * VDIM) / 8)   // 6,422,528 float8 items
#define NCONVB 3136                      // conv blocks (grid-stride x8)

typedef float  f32x4  __attribute__((ext_vector_type(4)));
typedef __bf16 bf16x8 __attribute__((ext_vector_type(8)));

__device__ __forceinline__ void gload_lds16(const void* g, void* l) {
    __builtin_amdgcn_global_load_lds(
        (const __attribute__((address_space(1))) void*)g,
        (__attribute__((address_space(3))) void*)l, 16, 0, 0);
}

__device__ __forceinline__ float fast_tanh(float x) {
    float ax = fabsf(x);
    float e  = __expf(-2.f * ax);          // in (0,1], no overflow
    float t  = (1.f - e) / (1.f + e);
    return copysignf(t, x);
}

// ---------------------------------------------------------------------------
// Kernel CP (merged):
//   [0,128):           whp = h@Ww + Wb + Ub   (unroll-8, 16 loads in flight)
//   [128,384):         Uw transpose -> UwT bf16
//   [384,384+convb):   V fp32 -> bf16 (grid-stride over N8)
// ---------------------------------------------------------------------------
__global__ void k_convprep(const float* __restrict__ V, __bf16* __restrict__ Vb,
                           const float* __restrict__ Uw, __bf16* __restrict__ UwT,
                           const float* __restrict__ h, const float* __restrict__ Ww,
                           const float* __restrict__ Wb, const float* __restrict__ Ub,
                           float* __restrict__ whp, int conv_blocks) {
    int t = threadIdx.x;  // 256
    if (blockIdx.x < 128) {
        __shared__ float hs[HDIM];
        int b = blockIdx.x;
        hs[t]       = h[(size_t)b * HDIM + t];
        hs[t + 256] = h[(size_t)b * HDIM + t + 256];
        __syncthreads();
        // unroll-8: 8 independent chains per column -> 16 loads in flight
        float a0[8] = {0,0,0,0,0,0,0,0}, a1[8] = {0,0,0,0,0,0,0,0};
        for (int k0 = 0; k0 < HDIM; k0 += 8) {
#pragma unroll
            for (int u = 0; u < 8; ++u) {
                float hv = hs[k0 + u];
                a0[u] += hv * Ww[(size_t)(k0 + u) * ATT + t];
                a1[u] += hv * Ww[(size_t)(k0 + u) * ATT + t + 256];
            }
        }
        float s0 = ((a0[0] + a0[1]) + (a0[2] + a0[3])) + ((a0[4] + a0[5]) + (a0[6] + a0[7]));
        float s1 = ((a1[0] + a1[1]) + (a1[2] + a1[3])) + ((a1[4] + a1[5]) + (a1[6] + a1[7]));
        whp[(size_t)b * ATT + t]       = s0 + Wb[t] + Ub[t];
        whp[(size_t)b * ATT + t + 256] = s1 + Wb[t + 256] + Ub[t + 256];
    } else if (blockIdx.x < 384) {
        __shared__ __bf16 st[64][65];
        int bb = blockIdx.x - 128;
        int k0 = (bb & 31) * 64;
        int c0 = (bb >> 5) * 64;
#pragma unroll
        for (int i = 0; i < 16; ++i) {
            int lin = i * 256 + t;
            int kk = lin >> 6, cc = lin & 63;
            st[kk][cc] = (__bf16)Uw[(size_t)(k0 + kk) * ATT + c0 + cc];
        }
        __syncthreads();
#pragma unroll
        for (int i = 0; i < 16; ++i) {
            int lin = i * 256 + t;
            int cc = lin >> 6, kk = lin & 63;
            UwT[(size_t)(c0 + cc) * VDIM + k0 + kk] = st[kk][cc];
        }
    } else {
        int cb = blockIdx.x - 384;           // 0..conv_blocks-1
        int stride = conv_blocks * 256;
        for (int i = cb * 256 + t; i < N8; i += stride) {
            const float4* s = reinterpret_cast<const float4*>(V + (size_t)i * 8);
            float4 x = s[0], y = s[1];
            bf16x8 w;
            w[0] = (__bf16)x.x; w[1] = (__bf16)x.y; w[2] = (__bf16)x.z; w[3] = (__bf16)x.w;
            w[4] = (__bf16)y.x; w[5] = (__bf16)y.y; w[6] = (__bf16)y.z; w[7] = (__bf16)y.w;
            reinterpret_cast<bf16x8*>(Vb)[i] = w;
        }
    }
}

// ---------------------------------------------------------------------------
// Kernel G (main): 128x128 tile, BK=64, 4 waves, counted-vmcnt depth-2
// pipeline, XOR-swizzled gload_lds both operands. [R7/R10-verified, ~21us]
// ---------------------------------------------------------------------------
__global__ __launch_bounds__(256, 2) void k_scores128(
    const __bf16* __restrict__ Vb, const __bf16* __restrict__ UwT,
    const float* __restrict__ whp, const float* __restrict__ vw,
    float* __restrict__ e_part)
{
    __shared__ __align__(16) __bf16 As[2][BM1][BKK];   // 32 KB
    __shared__ __align__(16) __bf16 Bs[2][BN1][BKK];   // 32 KB
    __shared__ float red[2][BM1];

    int bid = blockIdx.x;
    int lid = (bid & 7) * (784 / 8) + (bid >> 3);
    int mtile = lid >> 2;         // 0..195
    int cc    = lid & 3;          // 0..3
    int m0 = mtile * BM1;
    int c0 = cc * BN1;
    int t    = threadIdx.x;
    int lane = t & 63;
    int wave = t >> 6;
    int wr = wave >> 1;
    int wc = wave & 1;

    f32x4 acc[4][4];
#pragma unroll
    for (int i = 0; i < 4; ++i)
#pragma unroll
        for (int j = 0; j < 4; ++j) acc[i][j] = (f32x4){0.f, 0.f, 0.f, 0.f};

    int lr  = lane >> 3;
    int csw = ((lane & 7) ^ lr) * 8;
    const __bf16* AgS = Vb  + (size_t)(m0 + wave * 32 + lr) * VDIM + csw;
    const __bf16* BgS = UwT + (size_t)(c0 + wave * 32 + lr) * VDIM + csw;
    __bf16* Al0 = &As[0][wave * 32 + lr][(lane & 7) * 8];
    __bf16* Bl0 = &Bs[0][wave * 32 + lr][(lane & 7) * 8];

#define STAGE(buf, kt)                                                          \
    do {                                                                        \
        _Pragma("unroll")                                                       \
        for (int i = 0; i < 4; ++i) {                                           \
            gload_lds16(AgS + (kt) * BKK + (size_t)i * 8 * VDIM,                \
                        Al0 + (buf) * (BM1 * BKK) + i * 8 * BKK);               \
            gload_lds16(BgS + (kt) * BKK + (size_t)i * 8 * VDIM,                \
                        Bl0 + (buf) * (BN1 * BKK) + i * 8 * BKK);               \
        }                                                                       \
    } while (0)

    int lcol = lane & 15;
    int lg4  = lane >> 4;
    int arow0 = wr * 64;
    int bcol0 = wc * 64;

    STAGE(0, 0);
    __builtin_amdgcn_sched_barrier(0);   // pin issue order: tile0 before tile1
    STAGE(1, 1);

    for (int kt = 0; kt < NT; ++kt) {
        int buf = kt & 1;
        if (kt < NT - 1) {
            asm volatile("s_waitcnt vmcnt(8)\n\ts_barrier" ::: "memory");
        } else {
            asm volatile("s_waitcnt vmcnt(0)\n\ts_barrier" ::: "memory");
        }
        __builtin_amdgcn_sched_barrier(0);

#pragma unroll
        for (int ks = 0; ks < 2; ++ks) {
            bf16x8 af[4], bfr[4];
#pragma unroll
            for (int i = 0; i < 4; ++i) {
                int row = arow0 + i * 16 + lcol;
                int ch  = ((ks * 4 + lg4) ^ (row & 7)) * 8;
                af[i] = *reinterpret_cast<const bf16x8*>(&As[buf][row][ch]);
            }
#pragma unroll
            for (int j = 0; j < 4; ++j) {
                int row = bcol0 + j * 16 + lcol;
                int ch  = ((ks * 4 + lg4) ^ (row & 7)) * 8;
                bfr[j] = *reinterpret_cast<const bf16x8*>(&Bs[buf][row][ch]);
            }
            __builtin_amdgcn_s_setprio(1);
#pragma unroll
            for (int i = 0; i < 4; ++i)
#pragma unroll
                for (int j = 0; j < 4; ++j)
                    acc[i][j] = __builtin_amdgcn_mfma_f32_16x16x32_bf16(af[i], bfr[j], acc[i][j], 0, 0, 0);
            __builtin_amdgcn_s_setprio(0);
        }

        __builtin_amdgcn_sched_barrier(0);
        asm volatile("s_barrier" ::: "memory");   // buf free: all waves consumed it
        if (kt + 2 < NT) STAGE(buf, kt + 2);
    }
#undef STAGE

    // ---- epilogue: rowsum over this block's 128 cols ----
    int lrow4 = lg4 * 4;
#pragma unroll
    for (int i = 0; i < 4; ++i) {
        float rs[4] = {0.f, 0.f, 0.f, 0.f};
#pragma unroll
        for (int j = 0; j < 4; ++j) {
            int col = c0 + wc * 64 + j * 16 + lcol;
            float vwv = vw[col];
#pragma unroll
            for (int r = 0; r < 4; ++r) {
                int m = m0 + wr * 64 + i * 16 + lrow4 + r;
                int b = m / N_;
                float x = acc[i][j][r] + whp[(size_t)b * ATT + col];
                rs[r] += fast_tanh(x) * vwv;
            }
        }
#pragma unroll
        for (int r = 0; r < 4; ++r) {
            float v = rs[r];
            v += __shfl_xor(v, 1);
            v += __shfl_xor(v, 2);
            v += __shfl_xor(v, 4);
            v += __shfl_xor(v, 8);
            if (lcol == 0)
                red[wc][wr * 64 + i * 16 + lrow4 + r] = v;
        }
    }
    __syncthreads();
    if (t < BM1)
        e_part[(size_t)cc * M_TOT + m0 + t] = red[0][t] + red[1][t];
}

// ---------------------------------------------------------------------------
// Kernel G (fallback, no-ws path): 128x128, fp32 A reg-staged (R3-proven).
// ---------------------------------------------------------------------------
__global__ __launch_bounds__(256, 2) void k_scores_small(
    const float* __restrict__ Vf, const __bf16* __restrict__ UwT,
    const float* __restrict__ whp, const float* __restrict__ vw,
    float* __restrict__ e_part)
{
    __shared__ __align__(16) __bf16 As[2][BM1][BKK];
    __shared__ __align__(16) __bf16 Bs[2][BN1][BKK];
    __shared__ float red[2][BM1];

    int bid = blockIdx.x;
    int lid = (bid & 7) * (784 / 8) + (bid >> 3);
    int mtile = lid >> 2;
    int cc    = lid & 3;
    int m0 = mtile * BM1;
    int c0 = cc * BN1;
    int t    = threadIdx.x;
    int lane = t & 63;
    int wave = t >> 6;
    int wr = wave >> 1;
    int wc = wave & 1;

    f32x4 acc[4][4];
#pragma unroll
    for (int i = 0; i < 4; ++i)
#pragma unroll
        for (int j = 0; j < 4; ++j) acc[i][j] = (f32x4){0.f, 0.f, 0.f, 0.f};

    int lr  = lane >> 3;
    int csw = ((lane & 7) ^ lr) * 8;
    const __bf16* BgS = UwT + (size_t)(c0 + wave * 32 + lr) * VDIM + csw;
    __bf16* Bl0 = &Bs[0][wave * 32 + lr][(lane & 7) * 8];

    int ra = t >> 1;
    int ka = (t & 1) * 32;
    const float* Af = Vf + (size_t)(m0 + ra) * VDIM + ka;

#define STAGE1(buf, kt)                                                         \
    do {                                                                        \
        _Pragma("unroll")                                                       \
        for (int i = 0; i < 4; ++i)                                             \
            gload_lds16(BgS + (kt) * BKK + (size_t)i * 8 * VDIM,                \
                        Bl0 + (buf) * (BN1 * BKK) + i * 8 * BKK);               \
        const float4* src = reinterpret_cast<const float4*>(Af + (kt) * BKK);   \
        _Pragma("unroll")                                                       \
        for (int i = 0; i < 4; ++i) {                                           \
            float4 x = src[2 * i];                                              \
            float4 y = src[2 * i + 1];                                          \
            bf16x8 w;                                                           \
            w[0] = (__bf16)x.x; w[1] = (__bf16)x.y;                             \
            w[2] = (__bf16)x.z; w[3] = (__bf16)x.w;                             \
            w[4] = (__bf16)y.x; w[5] = (__bf16)y.y;                             \
            w[6] = (__bf16)y.z; w[7] = (__bf16)y.w;                             \
            int ch = (((t & 1) * 4 + i) ^ (ra & 7)) * 8;                        \
            *reinterpret_cast<bf16x8*>(&As[buf][ra][ch]) = w;                   \
        }                                                                       \
    } while (0)

    int lcol = lane & 15;
    int lg4  = lane >> 4;
    int arow0 = wr * 64;
    int bcol0 = wc * 64;

    STAGE1(0, 0);
    __syncthreads();

    for (int kt = 0; kt < NT; ++kt) {
        int buf = kt & 1;
        if (kt + 1 < NT) STAGE1(buf ^ 1, kt + 1);
#pragma unroll
        for (int ks = 0; ks < 2; ++ks) {
            bf16x8 af[4], bfr[4];
#pragma unroll
            for (int i = 0; i < 4; ++i) {
                int row = arow0 + i * 16 + lcol;
                int ch  = ((ks * 4 + lg4) ^ (row & 7)) * 8;
                af[i] = *reinterpret_cast<const bf16x8*>(&As[buf][row][ch]);
            }
#pragma unroll
            for (int j = 0; j < 4; ++j) {
                int row = bcol0 + j * 16 + lcol;
                int ch  = ((ks * 4 + lg4) ^ (row & 7)) * 8;
                bfr[j] = *reinterpret_cast<const bf16x8*>(&Bs[buf][row][ch]);
            }
#pragma unroll
            for (int i = 0; i < 4; ++i)
#pragma unroll
                for (int j = 0; j < 4; ++j)
                    acc[i][j] = __builtin_amdgcn_mfma_f32_16x16x32_bf16(af[i], bfr[j], acc[i][j], 0, 0, 0);
        }
        __syncthreads();
    }
#undef STAGE1

    int lrow4 = lg4 * 4;
#pragma unroll
    for (int i = 0; i < 4; ++i) {
        float rs[4] = {0.f, 0.f, 0.f, 0.f};
#pragma unroll
        for (int j = 0; j < 4; ++j) {
            int col = c0 + wc * 64 + j * 16 + lcol;
            float vwv = vw[col];
#pragma unroll
            for (int r = 0; r < 4; ++r) {
                int m = m0 + wr * 64 + i * 16 + lrow4 + r;
                int b = m / N_;
                float x = acc[i][j][r] + whp[(size_t)b * ATT + col];
                rs[r] += fast_tanh(x) * vwv;
            }
        }
#pragma unroll
        for (int r = 0; r < 4; ++r) {
            float v = rs[r];
            v += __shfl_xor(v, 1);
            v += __shfl_xor(v, 2);
            v += __shfl_xor(v, 4);
            v += __shfl_xor(v, 8);
            if (lcol == 0)
                red[wc][wr * 64 + i * 16 + lrow4 + r] = v;
        }
    }
    __syncthreads();
    if (t < BM1)
        e_part[(size_t)cc * M_TOT + m0 + t] = red[0][t] + red[1][t];
}

// ---------------------------------------------------------------------------
// Kernel CS (fused softmax + ctx, bf16 V): each (b,ch) block recomputes the
// softmax over N=196 from the 4 e-partials (identical fp ops -> identical a
// in both ch blocks, deterministic); ch==0 writes a_out; both accumulate ctx.
// ---------------------------------------------------------------------------
__global__ void k_ctx_sm(const __bf16* __restrict__ Vb, const float* __restrict__ e_part,
                         const float* __restrict__ vb, float* __restrict__ a_out,
                         float* __restrict__ ctx) {
    int b  = blockIdx.x;   // 128
    int ch = blockIdx.y;   // 2 chunks of 1024 cols
    int t  = threadIdx.x;  // 128
    __shared__ float sm[128];
    __shared__ float as_[N_];

    // softmax over N=196: thread t covers n=t and n=t+128
    int n0 = t, n1 = t + 128;
    float ev0 = 0.f, ev1 = 0.f, e0 = -1e30f, e1 = -1e30f;
    {
        int m = b * N_ + n0;
        ev0 = e_part[m] + e_part[M_TOT + m] + e_part[2 * M_TOT + m] + e_part[3 * M_TOT + m] + vb[0];
        e0 = ev0;   // n0 = t < 128 < 196 always valid
    }
    if (n1 < N_) {
        int m = b * N_ + n1;
        ev1 = e_part[m] + e_part[M_TOT + m] + e_part[2 * M_TOT + m] + e_part[3 * M_TOT + m] + vb[0];
        e1 = ev1;
    }
    sm[t] = fmaxf(e0, e1);
    __syncthreads();
    for (int s = 64; s > 0; s >>= 1) {
        if (t < s) sm[t] = fmaxf(sm[t], sm[t + s]);
        __syncthreads();
    }
    float mx = sm[0];
    __syncthreads();
    float x0 = __expf(ev0 - mx);
    float x1 = (n1 < N_) ? __expf(ev1 - mx) : 0.f;
    sm[t] = x0 + x1;
    __syncthreads();
    for (int s = 64; s > 0; s >>= 1) {
        if (t < s) sm[t] += sm[t + s];
        __syncthreads();
    }
    float inv = 1.f / sm[0];
    as_[n0] = x0 * inv;
    if (n1 < N_) as_[n1] = x1 * inv;
    if (ch == 0) {
        a_out[(size_t)b * N_ + n0] = x0 * inv;
        if (n1 < N_) a_out[(size_t)b * N_ + n1] = x1 * inv;
    }
    __syncthreads();

    // ctx accumulation: 8 cols/thread over this chunk of 1024
    int col = ch * 1024 + t * 8;
    const __bf16* Vp = Vb + (size_t)b * N_ * VDIM + col;
    float av[8] = {0.f, 0.f, 0.f, 0.f, 0.f, 0.f, 0.f, 0.f};
    for (int n = 0; n < N_; ++n) {
        bf16x8 v = *reinterpret_cast<const bf16x8*>(Vp + (size_t)n * VDIM);
        float an = as_[n];
#pragma unroll
        for (int j = 0; j < 8; ++j) av[j] += an * (float)v[j];
    }
    f32x4 lo = {av[0], av[1], av[2], av[3]};
    f32x4 hi = {av[4], av[5], av[6], av[7]};
    f32x4* dst = reinterpret_cast<f32x4*>(ctx + (size_t)b * VDIM + col);
    dst[0] = lo;
    dst[1] = hi;
}

// ---------------------------------------------------------------------------
// Fallback softmax + fp32 ctx (no-ws path)
// ---------------------------------------------------------------------------
__global__ void k_softmax(const float* __restrict__ e_part, const float* __restrict__ vb,
                          float* __restrict__ a_out) {
    int b = blockIdx.x;
    int t = threadIdx.x;  // 256
    __shared__ float sm[256];
    float ev = 0.f;
    float e  = -1e30f;
    if (t < N_) {
        int m = b * N_ + t;
        ev = e_part[m] + e_part[M_TOT + m] + e_part[2 * M_TOT + m] + e_part[3 * M_TOT + m] + vb[0];
        e = ev;
    }
    sm[t] = e;
    __syncthreads();
    for (int s = 128; s > 0; s >>= 1) {
        if (t < s) sm[t] = fmaxf(sm[t], sm[t + s]);
        __syncthreads();
    }
    float mx = sm[0];
    __syncthreads();
    float ex = (t < N_) ? __expf(ev - mx) : 0.f;
    sm[t] = ex;
    __syncthreads();
    for (int s = 128; s > 0; s >>= 1) {
        if (t < s) sm[t] += sm[t + s];
        __syncthreads();
    }
    float inv = 1.f / sm[0];
    if (t < N_) a_out[(size_t)b * N_ + t] = ex * inv;
}

__global__ void k_ctx_f32(const float* __restrict__ V, const float* __restrict__ a,
                          float* __restrict__ ctx) {
    int b  = blockIdx.x;
    int ch = blockIdx.y;
    int t  = threadIdx.x;  // 128
    __shared__ float as_[N_];
    for (int i = t; i < N_; i += 128) as_[i] = a[(size_t)b * N_ + i];
    __syncthreads();
    int col = ch * 512 + t * 4;
    const f32x4* Vp = reinterpret_cast<const f32x4*>(V + (size_t)b * N_ * VDIM + col);
    f32x4 accv = {0.f, 0.f, 0.f, 0.f};
    for (int n = 0; n < N_; ++n)
        accv += as_[n] * Vp[(size_t)n * (VDIM / 4)];
    *reinterpret_cast<f32x4*>(ctx + (size_t)b * VDIM + col) = accv;
}

// ---------------------------------------------------------------------------
extern "C" void kernel_launch(void* const* d_in, const int* in_sizes, int n_in,
                              void* d_out, int out_size, void* d_ws, size_t ws_size,
                              hipStream_t stream) {
    const float* h  = (const float*)d_in[0];
    const float* V  = (const float*)d_in[1];
    const float* Ww = (const float*)d_in[2];
    const float* Wb = (const float*)d_in[3];
    const float* Uw = (const float*)d_in[4];
    const float* Ub = (const float*)d_in[5];
    const float* vw = (const float*)d_in[6];
    const float* vb = (const float*)d_in[7];

    float* out     = (float*)d_out;
    float* ctx_out = out;                        // B*VDIM floats
    float* a_out   = out + (size_t)B_ * VDIM;    // B*N floats

    const size_t vb_bytes = (size_t)B_ * N_ * VDIM * sizeof(__bf16);  // ~103 MB
    const size_t tail     = 2u * 1024 * 1024 + 256 * 1024 + (size_t)4 * M_TOT * 4 + 4096;
    bool preconv = ws_size >= vb_bytes + tail;

    char*   ws   = (char*)d_ws;
    __bf16* Vb   = (__bf16*)ws;
    char*   rest = ws + (preconv ? vb_bytes : 0);
    __bf16* UwT   = (__bf16*)rest;
    float*  whp   = (float*)(rest + 2u * 1024 * 1024);
    float*  e_prt = (float*)(rest + 2u * 1024 * 1024 + 256 * 1024);

    int conv_blocks = preconv ? NCONVB : 0;
    k_convprep<<<dim3(384 + conv_blocks), 256, 0, stream>>>(
        V, Vb, Uw, UwT, h, Ww, Wb, Ub, whp, conv_blocks);
    if (preconv) {
        k_scores128<<<dim3(784), 256, 0, stream>>>(Vb, UwT, whp, vw, e_prt);
        k_ctx_sm<<<dim3(B_, 2), 128, 0, stream>>>(Vb, e_prt, vb, a_out, ctx_out);
    } else {
        k_scores_small<<<dim3(784), 256, 0, stream>>>(V, UwT, whp, vw, e_prt);
        k_softmax<<<dim3(B_), 256, 0, stream>>>(e_prt, vb, a_out);
        k_ctx_f32<<<dim3(B_, 4), 128, 0, stream>>>(V, a_out, ctx_out);
    }
}